// Round 7
// baseline (1181.462 us; speedup 1.0000x reference)
//
#include <hip/hip_runtime.h>

// Soft-DTW gradient, batch=64, 256x256, gamma=0.01 — single fused kernel.
// R7: same datapath as R6, but 8 blocks x 512 threads (8 waves/block ->
// 2 waves per SIMD) so co-resident waves hide each other's chain stalls.
// Wave w of block beta handles batch element b = 8*beta + w; lane t owns
// rows 4t+1..4t+4. 4-column skew (wave-uniform phase): lane t processes
// column-group g at macro-step m = g + t (fwd) / 126 - g - t (bwd).
// Forward stores softmin weights (wl, wu); backward is pure FMA, writes E
// in-place over Wl. Device-scope flag barrier (64 waves), then each wave
// reduces one 1024-word slice of out across the 64 E planes. No atomics
// on out. 3-phase rotating prefetch buffers (no register-rotation copies).
// ws: Wl/E planes [64][65536] f32, Wu planes [64][65536] f32, counter u32.

#define MM 256
#define NN 256
#define R 4
#define NL 64
#define NB 64            // batch elements / waves
#define NBLK 8           // blocks
#define WPB 8            // waves per block
#define BIGV 1.0e10f
#define K2   144.269504089f     // (1/gamma) * log2(e)
#define GLN2 0.00693147181f     // gamma * ln(2)

__device__ __forceinline__ float f4get(const float4& v, int k) {
    switch (k) { case 0: return v.x; case 1: return v.y; case 2: return v.z; default: return v.w; }
}
__device__ __forceinline__ int iclamp(int x, int lo, int hi) {
    return x < lo ? lo : (x > hi ? hi : x);
}
__device__ __forceinline__ float fast_rcp(float x) {
#if __has_builtin(__builtin_amdgcn_rcpf)
    return __builtin_amdgcn_rcpf(x);
#else
    return 1.0f / x;
#endif
}

__global__ __launch_bounds__(512) void dtw_fused(
    const float* __restrict__ D,
    float* __restrict__ out,          // [256][256]
    float* __restrict__ ws)
{
    const int w = threadIdx.x >> 6;                  // wave in block
    const int b = (blockIdx.x << 3) | w;             // batch element 0..63
    const int t = threadIdx.x & 63;                  // lane 0..63
    const float* __restrict__ th = D + (size_t)b * (MM * NN);
    float* __restrict__ Wl = ws + (size_t)b * (MM * NN);               // becomes E plane
    float* __restrict__ Wu = ws + (size_t)NB * (MM * NN) + (size_t)b * (MM * NN);
    unsigned* ctr = (unsigned*)(ws + (size_t)2 * NB * (MM * NN));

    // ---------------- forward ----------------
    {
        float vprev[R];
        #pragma unroll
        for (int r = 0; r < R; ++r) vprev[r] = BIGV;
        float4 rec = make_float4(BIGV, BIGV, BIGV, BIGV);
        float prevW = BIGV;
        float botV[4] = {BIGV, BIGV, BIGV, BIGV};
        float4 thB[3][R];
        #pragma unroll
        for (int p = 0; p < 3; ++p)
            #pragma unroll
            for (int r = 0; r < R; ++r) thB[p][r] = make_float4(0.f, 0.f, 0.f, 0.f);

        auto fwd_body = [&](const int LD, const int CU, const int m) {
            const int g = m - t;
            const int gl = iclamp(g + 2, 0, 63);
            #pragma unroll
            for (int r = 0; r < R; ++r)
                thB[LD][r] = *(const float4*)(th + (4 * t + r) * NN + 4 * gl);
            if (g >= 0 && g <= 63) {
                float4 topV = rec;
                if (t == 0) topV = make_float4(BIGV, BIGV, BIGV, BIGV);
                const float vd0 = (t == 0) ? ((g == 0) ? 0.0f : BIGV)
                                           : ((g == 0) ? BIGV : prevW);
                float wlb[R][4], wub[R][4];
                #pragma unroll
                for (int cc = 0; cc < 4; ++cc) {
                    float vu = f4get(topV, cc);
                    float vd = (cc == 0) ? vd0 : f4get(topV, cc - 1);
                    #pragma unroll
                    for (int r = 0; r < R; ++r) {
                        const float vl = vprev[r];
                        const float mn = fminf(vl, fminf(vd, vu));
                        const float el = exp2f((mn - vl) * K2);
                        const float ed = exp2f((mn - vd) * K2);
                        const float eu = exp2f((mn - vu) * K2);
                        const float ss = el + ed + eu;
                        const float ri = fast_rcp(ss);
                        const float a  = mn - GLN2 * log2f(ss);
                        const float v  = a + f4get(thB[CU][r], cc);
                        wlb[r][cc] = el * ri;
                        wub[r][cc] = eu * ri;
                        vd = vl;
                        vu = v;
                        vprev[r] = v;
                    }
                    botV[cc] = vprev[R - 1];
                }
                #pragma unroll
                for (int r = 0; r < R; ++r) {
                    *(float4*)(Wl + (4 * t + r) * NN + 4 * g) =
                        make_float4(wlb[r][0], wlb[r][1], wlb[r][2], wlb[r][3]);
                    *(float4*)(Wu + (4 * t + r) * NN + 4 * g) =
                        make_float4(wub[r][0], wub[r][1], wub[r][2], wub[r][3]);
                }
            }
            prevW = rec.w;
            rec.x = __shfl_up(botV[0], 1);
            rec.y = __shfl_up(botV[1], 1);
            rec.z = __shfl_up(botV[2], 1);
            rec.w = __shfl_up(botV[3], 1);
        };
        for (int k = 0; k < 129; k += 3) {      // m = k-2 : loads land 2 iters ahead
            fwd_body(0, 1, k - 2);
            fwd_body(1, 2, k - 1);
            fwd_body(2, 0, k);
        }
    }

    __threadfence();   // order forward weight-stores before backward loads

    // ---------------- backward (pure FMA, E -> Wl plane in place) ----------------
    {
        float eprev[R], prevWl[R], prevWu[R];
        #pragma unroll
        for (int r = 0; r < R; ++r) { eprev[r] = 0.0f; prevWl[r] = 0.0f; prevWu[r] = 0.0f; }
        float4 WlB[3][R], WuB[3][R];
        #pragma unroll
        for (int p = 0; p < 3; ++p)
            #pragma unroll
            for (int r = 0; r < R; ++r) {
                WlB[p][r] = make_float4(0.f, 0.f, 0.f, 0.f);
                WuB[p][r] = make_float4(0.f, 0.f, 0.f, 0.f);
            }
        float4 recWd = make_float4(0.f, 0.f, 0.f, 0.f);
        float4 recWu = recWd, recE = recWd;
        float pWd = 0.0f, pE = 0.0f;
        float topWd[4] = {0.f, 0.f, 0.f, 0.f};
        float topWu[4] = {0.f, 0.f, 0.f, 0.f};
        float topE[4]  = {0.f, 0.f, 0.f, 0.f};

        auto bwd_body = [&](const int LD, const int CU, const int m) {
            const int g = 126 - m - t;
            const int gl = iclamp(g - 2, 0, 63);
            #pragma unroll
            for (int r = 0; r < R; ++r) {
                WlB[LD][r] = *(const float4*)(Wl + (4 * t + r) * NN + 4 * gl);
                WuB[LD][r] = *(const float4*)(Wu + (4 * t + r) * NN + 4 * gl);
            }
            if (g >= 0 && g <= 63) {
                float4 rWd = recWd, rWu = recWu, rE = recE;
                if (t == NL - 1) {
                    rWd = make_float4(0.f, 0.f, 0.f, 0.f); rWu = rWd; rE = rWd;
                }
                const float pWd_ = (g == 63 || t == NL - 1) ? 0.0f : pWd;
                const float pE_  = (g == 63 || t == NL - 1) ? 0.0f : pE;
                float ebuf[R][4];
                #pragma unroll
                for (int cc = 3; cc >= 0; --cc) {
                    float bWd = (cc == 3) ? pWd_ : f4get(rWd, cc + 1);
                    float bEo = (cc == 3) ? pE_  : f4get(rE,  cc + 1);
                    float bWu = f4get(rWu, cc);
                    float bEn = f4get(rE,  cc);
                    #pragma unroll
                    for (int r = R - 1; r >= 0; --r) {
                        const float wlr = (cc == 3) ? prevWl[r] : f4get(WlB[CU][r], cc + 1);
                        float e = wlr * eprev[r] + bWd * bEo + bWu * bEn;
                        if (t == NL - 1 && r == R - 1 && g == 63 && cc == 3)
                            e = 1.0f;                                   // seed E(M,N)
                        ebuf[r][cc] = e;
                        const float wu_b = (cc == 3) ? prevWu[r] : f4get(WuB[CU][r], cc + 1);
                        bWd = 1.0f - wlr - wu_b;
                        bWu = f4get(WuB[CU][r], cc);
                        bEo = eprev[r];
                        bEn = e;
                        eprev[r] = e;
                    }
                }
                #pragma unroll
                for (int cc = 0; cc < 4; ++cc) {
                    topWd[cc] = 1.0f - f4get(WlB[CU][0], cc) - f4get(WuB[CU][0], cc);
                    topWu[cc] = f4get(WuB[CU][0], cc);
                    topE[cc]  = ebuf[0][cc];
                }
                #pragma unroll
                for (int r = 0; r < R; ++r)                     // E in place of Wl
                    *(float4*)(Wl + (4 * t + r) * NN + 4 * g) =
                        make_float4(ebuf[r][0], ebuf[r][1], ebuf[r][2], ebuf[r][3]);
            }
            pWd = recWd.x; pE = recE.x;
            #pragma unroll
            for (int r = 0; r < R; ++r) { prevWl[r] = WlB[CU][r].x; prevWu[r] = WuB[CU][r].x; }
            recWd.x = __shfl_down(topWd[0], 1);
            recWd.y = __shfl_down(topWd[1], 1);
            recWd.z = __shfl_down(topWd[2], 1);
            recWd.w = __shfl_down(topWd[3], 1);
            recWu.x = __shfl_down(topWu[0], 1);
            recWu.y = __shfl_down(topWu[1], 1);
            recWu.z = __shfl_down(topWu[2], 1);
            recWu.w = __shfl_down(topWu[3], 1);
            recE.x  = __shfl_down(topE[0], 1);
            recE.y  = __shfl_down(topE[1], 1);
            recE.z  = __shfl_down(topE[2], 1);
            recE.w  = __shfl_down(topE[3], 1);
        };
        for (int k = 0; k < 129; k += 3) {
            bwd_body(0, 1, k - 2);
            bwd_body(1, 2, k - 1);
            bwd_body(2, 0, k);
        }
    }

    // ---------------- device-scope barrier (64 waves) + slice reduction ----------------
    __threadfence();                               // release E stores (L2 writeback)
    if (t == 0)
        __hip_atomic_fetch_add(ctr, 1u, __ATOMIC_ACQ_REL, __HIP_MEMORY_SCOPE_AGENT);
    unsigned cnt;
    do {
        cnt = __hip_atomic_load(ctr, __ATOMIC_ACQUIRE, __HIP_MEMORY_SCOPE_AGENT);
        if (cnt < NB) __builtin_amdgcn_s_sleep(2);
    } while (cnt < NB);
    __builtin_amdgcn_fence(__ATOMIC_ACQUIRE, "agent");   // invalidate caches

    {
        const float* Eall = ws;                    // Wl planes now hold E
        float4 acc[4];
        #pragma unroll
        for (int k2 = 0; k2 < 4; ++k2) acc[k2] = make_float4(0.f, 0.f, 0.f, 0.f);
        for (int p = 0; p < NB; ++p) {
            const float* Ep = Eall + (size_t)p * (MM * NN);
            #pragma unroll
            for (int k2 = 0; k2 < 4; ++k2) {
                const float4 v = *(const float4*)(Ep + 1024 * b + 256 * k2 + 4 * t);
                acc[k2].x += v.x; acc[k2].y += v.y; acc[k2].z += v.z; acc[k2].w += v.w;
            }
        }
        const float inv = 1.0f / (float)NB;
        #pragma unroll
        for (int k2 = 0; k2 < 4; ++k2)
            *(float4*)(out + 1024 * b + 256 * k2 + 4 * t) =
                make_float4(acc[k2].x * inv, acc[k2].y * inv, acc[k2].z * inv, acc[k2].w * inv);
    }
}

extern "C" void kernel_launch(void* const* d_in, const int* in_sizes, int n_in,
                              void* d_out, int out_size, void* d_ws, size_t ws_size,
                              hipStream_t stream) {
    const float* D = (const float*)d_in[0];
    float* out = (float*)d_out;
    float* ws = (float*)d_ws;

    // zero the barrier counter (ws is re-poisoned 0xAA before every launch)
    hipMemsetAsync(ws + (size_t)2 * NB * (MM * NN), 0, sizeof(unsigned), stream);
    dtw_fused<<<dim3(NBLK), dim3(NBLK * 64), 0, stream>>>(D, out, ws);
}

// Round 8
// 437.019 us; speedup vs baseline: 2.7035x; 2.7035x over previous
//
#include <hip/hip_runtime.h>

// Soft-DTW gradient, batch=64, 256x256, gamma=0.01 — single fused kernel.
// R8: identical datapath to R6 (best: 316us), but 32 blocks x 128 threads:
// 2 waves per block -> 2 different SIMDs of the SAME CU, each wave one batch
// element (b = 2*blockIdx + w). No SIMD sharing (R7's 2-waves/SIMD mistake),
// L1 traffic only 2x (not 8x) -> co-resident wave hides latency stalls.
// Lane t owns rows 4t+1..4t+4. 4-column skew (wave-uniform phase).
// Forward stores softmin weights (wl, wu); backward pure FMA, E in-place
// over Wl. Device-scope flag barrier (64 waves), then per-wave slice
// reduction. No atomics on out. 3-phase rotating prefetch buffers.
// ws: Wl/E planes [64][65536] f32, Wu planes [64][65536] f32, counter u32.

#define MM 256
#define NN 256
#define R 4
#define NL 64
#define NB 64            // batch elements / waves
#define NBLK 32          // blocks (2 waves each)
#define BIGV 1.0e10f
#define K2   144.269504089f     // (1/gamma) * log2(e)
#define GLN2 0.00693147181f     // gamma * ln(2)

__device__ __forceinline__ float f4get(const float4& v, int k) {
    switch (k) { case 0: return v.x; case 1: return v.y; case 2: return v.z; default: return v.w; }
}
__device__ __forceinline__ int iclamp(int x, int lo, int hi) {
    return x < lo ? lo : (x > hi ? hi : x);
}
__device__ __forceinline__ float fast_rcp(float x) {
#if __has_builtin(__builtin_amdgcn_rcpf)
    return __builtin_amdgcn_rcpf(x);
#else
    return 1.0f / x;
#endif
}

__global__ __launch_bounds__(128) void dtw_fused(
    const float* __restrict__ D,
    float* __restrict__ out,          // [256][256]
    float* __restrict__ ws)
{
    const int w = threadIdx.x >> 6;                  // wave in block (0/1)
    const int b = (blockIdx.x << 1) | w;             // batch element 0..63
    const int t = threadIdx.x & 63;                  // lane 0..63
    const float* __restrict__ th = D + (size_t)b * (MM * NN);
    float* __restrict__ Wl = ws + (size_t)b * (MM * NN);               // becomes E plane
    float* __restrict__ Wu = ws + (size_t)NB * (MM * NN) + (size_t)b * (MM * NN);
    unsigned* ctr = (unsigned*)(ws + (size_t)2 * NB * (MM * NN));

    // ---------------- forward ----------------
    {
        float vprev[R];
        #pragma unroll
        for (int r = 0; r < R; ++r) vprev[r] = BIGV;
        float4 rec = make_float4(BIGV, BIGV, BIGV, BIGV);
        float prevW = BIGV;
        float botV[4] = {BIGV, BIGV, BIGV, BIGV};
        float4 thB[3][R];
        #pragma unroll
        for (int p = 0; p < 3; ++p)
            #pragma unroll
            for (int r = 0; r < R; ++r) thB[p][r] = make_float4(0.f, 0.f, 0.f, 0.f);

        auto fwd_body = [&](const int LD, const int CU, const int m) {
            const int g = m - t;
            const int gl = iclamp(g + 2, 0, 63);
            #pragma unroll
            for (int r = 0; r < R; ++r)
                thB[LD][r] = *(const float4*)(th + (4 * t + r) * NN + 4 * gl);
            if (g >= 0 && g <= 63) {
                float4 topV = rec;
                if (t == 0) topV = make_float4(BIGV, BIGV, BIGV, BIGV);
                const float vd0 = (t == 0) ? ((g == 0) ? 0.0f : BIGV)
                                           : ((g == 0) ? BIGV : prevW);
                float wlb[R][4], wub[R][4];
                #pragma unroll
                for (int cc = 0; cc < 4; ++cc) {
                    float vu = f4get(topV, cc);
                    float vd = (cc == 0) ? vd0 : f4get(topV, cc - 1);
                    #pragma unroll
                    for (int r = 0; r < R; ++r) {
                        const float vl = vprev[r];
                        const float mn = fminf(vl, fminf(vd, vu));
                        const float el = exp2f((mn - vl) * K2);
                        const float ed = exp2f((mn - vd) * K2);
                        const float eu = exp2f((mn - vu) * K2);
                        const float ss = el + ed + eu;
                        const float ri = fast_rcp(ss);
                        const float a  = mn - GLN2 * log2f(ss);
                        const float v  = a + f4get(thB[CU][r], cc);
                        wlb[r][cc] = el * ri;
                        wub[r][cc] = eu * ri;
                        vd = vl;
                        vu = v;
                        vprev[r] = v;
                    }
                    botV[cc] = vprev[R - 1];
                }
                #pragma unroll
                for (int r = 0; r < R; ++r) {
                    *(float4*)(Wl + (4 * t + r) * NN + 4 * g) =
                        make_float4(wlb[r][0], wlb[r][1], wlb[r][2], wlb[r][3]);
                    *(float4*)(Wu + (4 * t + r) * NN + 4 * g) =
                        make_float4(wub[r][0], wub[r][1], wub[r][2], wub[r][3]);
                }
            }
            prevW = rec.w;
            rec.x = __shfl_up(botV[0], 1);
            rec.y = __shfl_up(botV[1], 1);
            rec.z = __shfl_up(botV[2], 1);
            rec.w = __shfl_up(botV[3], 1);
        };
        for (int k = 0; k < 129; k += 3) {      // m = k-2 : loads land 2 iters ahead
            fwd_body(0, 1, k - 2);
            fwd_body(1, 2, k - 1);
            fwd_body(2, 0, k);
        }
    }

    __threadfence();   // order forward weight-stores before backward loads

    // ---------------- backward (pure FMA, E -> Wl plane in place) ----------------
    {
        float eprev[R], prevWl[R], prevWu[R];
        #pragma unroll
        for (int r = 0; r < R; ++r) { eprev[r] = 0.0f; prevWl[r] = 0.0f; prevWu[r] = 0.0f; }
        float4 WlB[3][R], WuB[3][R];
        #pragma unroll
        for (int p = 0; p < 3; ++p)
            #pragma unroll
            for (int r = 0; r < R; ++r) {
                WlB[p][r] = make_float4(0.f, 0.f, 0.f, 0.f);
                WuB[p][r] = make_float4(0.f, 0.f, 0.f, 0.f);
            }
        float4 recWd = make_float4(0.f, 0.f, 0.f, 0.f);
        float4 recWu = recWd, recE = recWd;
        float pWd = 0.0f, pE = 0.0f;
        float topWd[4] = {0.f, 0.f, 0.f, 0.f};
        float topWu[4] = {0.f, 0.f, 0.f, 0.f};
        float topE[4]  = {0.f, 0.f, 0.f, 0.f};

        auto bwd_body = [&](const int LD, const int CU, const int m) {
            const int g = 126 - m - t;
            const int gl = iclamp(g - 2, 0, 63);
            #pragma unroll
            for (int r = 0; r < R; ++r) {
                WlB[LD][r] = *(const float4*)(Wl + (4 * t + r) * NN + 4 * gl);
                WuB[LD][r] = *(const float4*)(Wu + (4 * t + r) * NN + 4 * gl);
            }
            if (g >= 0 && g <= 63) {
                float4 rWd = recWd, rWu = recWu, rE = recE;
                if (t == NL - 1) {
                    rWd = make_float4(0.f, 0.f, 0.f, 0.f); rWu = rWd; rE = rWd;
                }
                const float pWd_ = (g == 63 || t == NL - 1) ? 0.0f : pWd;
                const float pE_  = (g == 63 || t == NL - 1) ? 0.0f : pE;
                float ebuf[R][4];
                #pragma unroll
                for (int cc = 3; cc >= 0; --cc) {
                    float bWd = (cc == 3) ? pWd_ : f4get(rWd, cc + 1);
                    float bEo = (cc == 3) ? pE_  : f4get(rE,  cc + 1);
                    float bWu = f4get(rWu, cc);
                    float bEn = f4get(rE,  cc);
                    #pragma unroll
                    for (int r = R - 1; r >= 0; --r) {
                        const float wlr = (cc == 3) ? prevWl[r] : f4get(WlB[CU][r], cc + 1);
                        float e = wlr * eprev[r] + bWd * bEo + bWu * bEn;
                        if (t == NL - 1 && r == R - 1 && g == 63 && cc == 3)
                            e = 1.0f;                                   // seed E(M,N)
                        ebuf[r][cc] = e;
                        const float wu_b = (cc == 3) ? prevWu[r] : f4get(WuB[CU][r], cc + 1);
                        bWd = 1.0f - wlr - wu_b;
                        bWu = f4get(WuB[CU][r], cc);
                        bEo = eprev[r];
                        bEn = e;
                        eprev[r] = e;
                    }
                }
                #pragma unroll
                for (int cc = 0; cc < 4; ++cc) {
                    topWd[cc] = 1.0f - f4get(WlB[CU][0], cc) - f4get(WuB[CU][0], cc);
                    topWu[cc] = f4get(WuB[CU][0], cc);
                    topE[cc]  = ebuf[0][cc];
                }
                #pragma unroll
                for (int r = 0; r < R; ++r)                     // E in place of Wl
                    *(float4*)(Wl + (4 * t + r) * NN + 4 * g) =
                        make_float4(ebuf[r][0], ebuf[r][1], ebuf[r][2], ebuf[r][3]);
            }
            pWd = recWd.x; pE = recE.x;
            #pragma unroll
            for (int r = 0; r < R; ++r) { prevWl[r] = WlB[CU][r].x; prevWu[r] = WuB[CU][r].x; }
            recWd.x = __shfl_down(topWd[0], 1);
            recWd.y = __shfl_down(topWd[1], 1);
            recWd.z = __shfl_down(topWd[2], 1);
            recWd.w = __shfl_down(topWd[3], 1);
            recWu.x = __shfl_down(topWu[0], 1);
            recWu.y = __shfl_down(topWu[1], 1);
            recWu.z = __shfl_down(topWu[2], 1);
            recWu.w = __shfl_down(topWu[3], 1);
            recE.x  = __shfl_down(topE[0], 1);
            recE.y  = __shfl_down(topE[1], 1);
            recE.z  = __shfl_down(topE[2], 1);
            recE.w  = __shfl_down(topE[3], 1);
        };
        for (int k = 0; k < 129; k += 3) {
            bwd_body(0, 1, k - 2);
            bwd_body(1, 2, k - 1);
            bwd_body(2, 0, k);
        }
    }

    // ---------------- device-scope barrier (64 waves) + slice reduction ----------------
    __threadfence();                               // release E stores (L2 writeback)
    if (t == 0)
        __hip_atomic_fetch_add(ctr, 1u, __ATOMIC_ACQ_REL, __HIP_MEMORY_SCOPE_AGENT);
    unsigned cnt;
    do {
        cnt = __hip_atomic_load(ctr, __ATOMIC_ACQUIRE, __HIP_MEMORY_SCOPE_AGENT);
        if (cnt < NB) __builtin_amdgcn_s_sleep(2);
    } while (cnt < NB);
    __builtin_amdgcn_fence(__ATOMIC_ACQUIRE, "agent");   // invalidate caches

    {
        const float* Eall = ws;                    // Wl planes now hold E
        float4 acc[4];
        #pragma unroll
        for (int k2 = 0; k2 < 4; ++k2) acc[k2] = make_float4(0.f, 0.f, 0.f, 0.f);
        for (int p = 0; p < NB; ++p) {
            const float* Ep = Eall + (size_t)p * (MM * NN);
            #pragma unroll
            for (int k2 = 0; k2 < 4; ++k2) {
                const float4 v = *(const float4*)(Ep + 1024 * b + 256 * k2 + 4 * t);
                acc[k2].x += v.x; acc[k2].y += v.y; acc[k2].z += v.z; acc[k2].w += v.w;
            }
        }
        const float inv = 1.0f / (float)NB;
        #pragma unroll
        for (int k2 = 0; k2 < 4; ++k2)
            *(float4*)(out + 1024 * b + 256 * k2 + 4 * t) =
                make_float4(acc[k2].x * inv, acc[k2].y * inv, acc[k2].z * inv, acc[k2].w * inv);
    }
}

extern "C" void kernel_launch(void* const* d_in, const int* in_sizes, int n_in,
                              void* d_out, int out_size, void* d_ws, size_t ws_size,
                              hipStream_t stream) {
    const float* D = (const float*)d_in[0];
    float* out = (float*)d_out;
    float* ws = (float*)d_ws;

    // zero the barrier counter (ws is re-poisoned 0xAA before every launch)
    hipMemsetAsync(ws + (size_t)2 * NB * (MM * NN), 0, sizeof(unsigned), stream);
    dtw_fused<<<dim3(NBLK), dim3(128), 0, stream>>>(D, out, ws);
}

// Round 10
// 343.661 us; speedup vs baseline: 3.4379x; 1.2717x over previous
//
#include <hip/hip_runtime.h>

// Soft-DTW gradient, batch=64, 256x256, gamma=0.01 — single fused kernel.
// R10 = R9 + bugfix: restore the prevWl/prevWu capture in bwd_body (dropped
// in R9; without it every group-boundary column used wl=0 -> absmax 1.4).
// Layout: 64 blocks x 128 threads. Each block = one batch element, TWO waves
// on different SIMDs of one CU. Virtual lane L = 64*w + t owns rows 2L+1,
// 2L+2 (R=2). 4-column skew: lane L processes column-group g at macro-step
// m = g + L (fwd) / m = 190 - g - L (bwd). Within-wave handoff via shuffles;
// wave0-lane63 <-> wave1-lane0 boundary via 2-slot LDS buffer + ONE
// __syncthreads per macro-step. Forward stores softmin weights (wl, wu);
// backward pure FMA, E in-place over Wl. Device-scope flag barrier, then
// per-block slice reduction. No atomics on out. 3-phase rotating prefetch.
// ws: Wl/E planes [64][65536] f32, Wu planes [64][65536] f32, counter u32.

#define MM 256
#define NN 256
#define R 2              // rows per virtual lane
#define NB 64            // batch elements / blocks
#define NVL 128          // virtual lanes per element
#define BIGV 1.0e10f
#define K2   144.269504089f     // (1/gamma) * log2(e)
#define GLN2 0.00693147181f     // gamma * ln(2)

__device__ __forceinline__ float f4get(const float4& v, int k) {
    switch (k) { case 0: return v.x; case 1: return v.y; case 2: return v.z; default: return v.w; }
}
__device__ __forceinline__ int iclamp(int x, int lo, int hi) {
    return x < lo ? lo : (x > hi ? hi : x);
}
__device__ __forceinline__ float fast_rcp(float x) {
#if __has_builtin(__builtin_amdgcn_rcpf)
    return __builtin_amdgcn_rcpf(x);
#else
    return 1.0f / x;
#endif
}

__global__ __launch_bounds__(128) void dtw_fused(
    const float* __restrict__ D,
    float* __restrict__ out,          // [256][256]
    float* __restrict__ ws)
{
    const int b = blockIdx.x;                        // batch element
    const int w = threadIdx.x >> 6;                  // wave 0/1
    const int t = threadIdx.x & 63;                  // lane in wave
    const int L = (w << 6) | t;                      // virtual lane 0..127
    const float* __restrict__ th = D + (size_t)b * (MM * NN);
    float* __restrict__ Wl = ws + (size_t)b * (MM * NN);               // becomes E plane
    float* __restrict__ Wu = ws + (size_t)NB * (MM * NN) + (size_t)b * (MM * NN);
    unsigned* ctr = (unsigned*)(ws + (size_t)2 * NB * (MM * NN));

    __shared__ float hsF[2][4];       // fwd handoff: wave0-lane63 botV
    __shared__ float hsB[2][12];      // bwd handoff: wave1-lane0 topWd/topWu/topE

    // ---------------- forward ----------------
    {
        float vprev[R];
        #pragma unroll
        for (int r = 0; r < R; ++r) vprev[r] = BIGV;
        float4 rec = make_float4(BIGV, BIGV, BIGV, BIGV);
        float prevW = BIGV;
        float botV[4] = {BIGV, BIGV, BIGV, BIGV};
        float4 thB[3][R];
        #pragma unroll
        for (int p = 0; p < 3; ++p)
            #pragma unroll
            for (int r = 0; r < R; ++r) thB[p][r] = make_float4(0.f, 0.f, 0.f, 0.f);

        auto fwd_body = [&](const int LD, const int CU, const int m) {
            const int g = m - L;
            const int gl = iclamp(g + 2, 0, 63);
            #pragma unroll
            for (int r = 0; r < R; ++r)
                thB[LD][r] = *(const float4*)(th + (2 * L + r) * NN + 4 * gl);
            if (g >= 0 && g <= 63) {
                float4 topV = rec;
                if (L == 0) topV = make_float4(BIGV, BIGV, BIGV, BIGV);
                const float vd0 = (L == 0) ? ((g == 0) ? 0.0f : BIGV)
                                           : ((g == 0) ? BIGV : prevW);
                float wlb[R][4], wub[R][4];
                #pragma unroll
                for (int cc = 0; cc < 4; ++cc) {
                    float vu = f4get(topV, cc);
                    float vd = (cc == 0) ? vd0 : f4get(topV, cc - 1);
                    #pragma unroll
                    for (int r = 0; r < R; ++r) {
                        const float vl = vprev[r];
                        const float mn = fminf(vl, fminf(vd, vu));
                        const float el = exp2f((mn - vl) * K2);
                        const float ed = exp2f((mn - vd) * K2);
                        const float eu = exp2f((mn - vu) * K2);
                        const float ss = el + ed + eu;
                        const float ri = fast_rcp(ss);
                        const float a  = mn - GLN2 * log2f(ss);
                        const float v  = a + f4get(thB[CU][r], cc);
                        wlb[r][cc] = el * ri;
                        wub[r][cc] = eu * ri;
                        vd = vl;
                        vu = v;
                        vprev[r] = v;
                    }
                    botV[cc] = vprev[R - 1];
                }
                #pragma unroll
                for (int r = 0; r < R; ++r) {
                    *(float4*)(Wl + (2 * L + r) * NN + 4 * g) =
                        make_float4(wlb[r][0], wlb[r][1], wlb[r][2], wlb[r][3]);
                    *(float4*)(Wu + (2 * L + r) * NN + 4 * g) =
                        make_float4(wub[r][0], wub[r][1], wub[r][2], wub[r][3]);
                }
            }
            // ---- handoff + rotate ----
            if (w == 0 && t == 63) {
                hsF[m & 1][0] = botV[0]; hsF[m & 1][1] = botV[1];
                hsF[m & 1][2] = botV[2]; hsF[m & 1][3] = botV[3];
            }
            __syncthreads();
            prevW = rec.w;
            rec.x = __shfl_up(botV[0], 1);
            rec.y = __shfl_up(botV[1], 1);
            rec.z = __shfl_up(botV[2], 1);
            rec.w = __shfl_up(botV[3], 1);
            if (w == 1 && t == 0) {
                rec.x = hsF[m & 1][0]; rec.y = hsF[m & 1][1];
                rec.z = hsF[m & 1][2]; rec.w = hsF[m & 1][3];
            }
        };
        for (int k = 0; k < 195; k += 3) {      // m = -2 .. 192
            fwd_body(0, 1, k - 2);
            fwd_body(1, 2, k - 1);
            fwd_body(2, 0, k);
        }
    }

    __threadfence();   // order forward weight-stores before backward loads

    // ---------------- backward (pure FMA, E -> Wl plane in place) ----------------
    {
        float eprev[R], prevWl[R], prevWu[R];
        #pragma unroll
        for (int r = 0; r < R; ++r) { eprev[r] = 0.0f; prevWl[r] = 0.0f; prevWu[r] = 0.0f; }
        float4 WlB[3][R], WuB[3][R];
        #pragma unroll
        for (int p = 0; p < 3; ++p)
            #pragma unroll
            for (int r = 0; r < R; ++r) {
                WlB[p][r] = make_float4(0.f, 0.f, 0.f, 0.f);
                WuB[p][r] = make_float4(0.f, 0.f, 0.f, 0.f);
            }
        float4 recWd = make_float4(0.f, 0.f, 0.f, 0.f);
        float4 recWu = recWd, recE = recWd;
        float pWd = 0.0f, pE = 0.0f;
        float topWd[4] = {0.f, 0.f, 0.f, 0.f};
        float topWu[4] = {0.f, 0.f, 0.f, 0.f};
        float topE[4]  = {0.f, 0.f, 0.f, 0.f};

        auto bwd_body = [&](const int LD, const int CU, const int m) {
            const int g = 190 - m - L;
            const int gl = iclamp(g - 2, 0, 63);
            #pragma unroll
            for (int r = 0; r < R; ++r) {
                WlB[LD][r] = *(const float4*)(Wl + (2 * L + r) * NN + 4 * gl);
                WuB[LD][r] = *(const float4*)(Wu + (2 * L + r) * NN + 4 * gl);
            }
            if (g >= 0 && g <= 63) {
                float4 rWd = recWd, rWu = recWu, rE = recE;
                if (L == NVL - 1) {
                    rWd = make_float4(0.f, 0.f, 0.f, 0.f); rWu = rWd; rE = rWd;
                }
                const float pWd_ = (g == 63 || L == NVL - 1) ? 0.0f : pWd;
                const float pE_  = (g == 63 || L == NVL - 1) ? 0.0f : pE;
                float ebuf[R][4];
                #pragma unroll
                for (int cc = 3; cc >= 0; --cc) {
                    float bWd = (cc == 3) ? pWd_ : f4get(rWd, cc + 1);
                    float bEo = (cc == 3) ? pE_  : f4get(rE,  cc + 1);
                    float bWu = f4get(rWu, cc);
                    float bEn = f4get(rE,  cc);
                    #pragma unroll
                    for (int r = R - 1; r >= 0; --r) {
                        const float wlr = (cc == 3) ? prevWl[r] : f4get(WlB[CU][r], cc + 1);
                        float e = wlr * eprev[r] + bWd * bEo + bWu * bEn;
                        if (L == NVL - 1 && r == R - 1 && g == 63 && cc == 3)
                            e = 1.0f;                                   // seed E(M,N)
                        ebuf[r][cc] = e;
                        const float wu_b = (cc == 3) ? prevWu[r] : f4get(WuB[CU][r], cc + 1);
                        bWd = 1.0f - wlr - wu_b;
                        bWu = f4get(WuB[CU][r], cc);
                        bEo = eprev[r];
                        bEn = e;
                        eprev[r] = e;
                    }
                }
                #pragma unroll
                for (int cc = 0; cc < 4; ++cc) {
                    topWd[cc] = 1.0f - f4get(WlB[CU][0], cc) - f4get(WuB[CU][0], cc);
                    topWu[cc] = f4get(WuB[CU][0], cc);
                    topE[cc]  = ebuf[0][cc];
                }
                #pragma unroll
                for (int r = 0; r < R; ++r)                     // E in place of Wl
                    *(float4*)(Wl + (2 * L + r) * NN + 4 * g) =
                        make_float4(ebuf[r][0], ebuf[r][1], ebuf[r][2], ebuf[r][3]);
            }
            // ---- handoff + rotate ----
            if (w == 1 && t == 0) {
                #pragma unroll
                for (int cc = 0; cc < 4; ++cc) {
                    hsB[m & 1][cc]     = topWd[cc];
                    hsB[m & 1][4 + cc] = topWu[cc];
                    hsB[m & 1][8 + cc] = topE[cc];
                }
            }
            __syncthreads();
            pWd = recWd.x; pE = recE.x;
            #pragma unroll
            for (int r = 0; r < R; ++r) {        // R10 bugfix: own-row W at next
                prevWl[r] = WlB[CU][r].x;        // group's col0 (consumed by the
                prevWu[r] = WuB[CU][r].x;        // cc==3 case next macro-step)
            }
            recWd.x = __shfl_down(topWd[0], 1);
            recWd.y = __shfl_down(topWd[1], 1);
            recWd.z = __shfl_down(topWd[2], 1);
            recWd.w = __shfl_down(topWd[3], 1);
            recWu.x = __shfl_down(topWu[0], 1);
            recWu.y = __shfl_down(topWu[1], 1);
            recWu.z = __shfl_down(topWu[2], 1);
            recWu.w = __shfl_down(topWu[3], 1);
            recE.x  = __shfl_down(topE[0], 1);
            recE.y  = __shfl_down(topE[1], 1);
            recE.z  = __shfl_down(topE[2], 1);
            recE.w  = __shfl_down(topE[3], 1);
            if (w == 0 && t == 63) {
                recWd.x = hsB[m & 1][0];  recWd.y = hsB[m & 1][1];
                recWd.z = hsB[m & 1][2];  recWd.w = hsB[m & 1][3];
                recWu.x = hsB[m & 1][4];  recWu.y = hsB[m & 1][5];
                recWu.z = hsB[m & 1][6];  recWu.w = hsB[m & 1][7];
                recE.x  = hsB[m & 1][8];  recE.y  = hsB[m & 1][9];
                recE.z  = hsB[m & 1][10]; recE.w  = hsB[m & 1][11];
            }
        };
        for (int k = 0; k < 195; k += 3) {      // m = -2 .. 192
            bwd_body(0, 1, k - 2);
            bwd_body(1, 2, k - 1);
            bwd_body(2, 0, k);
        }
    }

    // ---------------- device-scope barrier (64 blocks) + slice reduction ----------------
    __threadfence();                               // release E stores (L2 writeback)
    if (threadIdx.x == 0)
        __hip_atomic_fetch_add(ctr, 1u, __ATOMIC_ACQ_REL, __HIP_MEMORY_SCOPE_AGENT);
    unsigned cnt;
    do {
        cnt = __hip_atomic_load(ctr, __ATOMIC_ACQUIRE, __HIP_MEMORY_SCOPE_AGENT);
        if (cnt < NB) __builtin_amdgcn_s_sleep(2);
    } while (cnt < NB);
    __builtin_amdgcn_fence(__ATOMIC_ACQUIRE, "agent");   // invalidate caches

    {
        const float* Eall = ws;                    // Wl planes now hold E
        float4 acc[2];
        #pragma unroll
        for (int k2 = 0; k2 < 2; ++k2) acc[k2] = make_float4(0.f, 0.f, 0.f, 0.f);
        for (int p = 0; p < NB; ++p) {
            const float* Ep = Eall + (size_t)p * (MM * NN);
            #pragma unroll
            for (int k2 = 0; k2 < 2; ++k2) {
                const float4 v = *(const float4*)(Ep + 1024 * b + 512 * k2 + 4 * threadIdx.x);
                acc[k2].x += v.x; acc[k2].y += v.y; acc[k2].z += v.z; acc[k2].w += v.w;
            }
        }
        const float inv = 1.0f / (float)NB;
        #pragma unroll
        for (int k2 = 0; k2 < 2; ++k2)
            *(float4*)(out + 1024 * b + 512 * k2 + 4 * threadIdx.x) =
                make_float4(acc[k2].x * inv, acc[k2].y * inv, acc[k2].z * inv, acc[k2].w * inv);
    }
}

extern "C" void kernel_launch(void* const* d_in, const int* in_sizes, int n_in,
                              void* d_out, int out_size, void* d_ws, size_t ws_size,
                              hipStream_t stream) {
    const float* D = (const float*)d_in[0];
    float* out = (float*)d_out;
    float* ws = (float*)d_ws;

    // zero the barrier counter (ws is re-poisoned 0xAA before every launch)
    hipMemsetAsync(ws + (size_t)2 * NB * (MM * NN), 0, sizeof(unsigned), stream);
    dtw_fused<<<dim3(NB), dim3(128), 0, stream>>>(D, out, ws);
}

// Round 11
// 329.693 us; speedup vs baseline: 3.5835x; 1.0424x over previous
//
#include <hip/hip_runtime.h>

// Soft-DTW gradient, batch=64, 256x256, gamma=0.01 — single fused kernel.
// R11 = R10 datapath + uniform LDS neighbor-exchange: all cross-lane
// handoffs (previously 16 shuffles + divergent wave-boundary LDS blocks)
// become branch-free double-buffered LDS slots with sentinel entries
// (slot 0 = BIGV for fwd, slot NVL = 0 for bwd). One __syncthreads per
// macro-step, same as R10.
// Layout: 64 blocks x 128 threads. Each block = one batch element, two
// waves on different SIMDs of one CU. Virtual lane L = 64*w + t owns rows
// 2L+1, 2L+2 (R=2). 4-column skew: lane L does column-group g at
// macro-step m = g + L (fwd) / m = 190 - g - L (bwd).
// Forward stores softmin weights (wl, wu); backward pure FMA, E in-place
// over Wl. Device-scope flag barrier, then per-block slice reduction.
// No atomics on out. 3-phase rotating prefetch buffers.
// ws: Wl/E planes [64][65536] f32, Wu planes [64][65536] f32, counter u32.

#define MM 256
#define NN 256
#define R 2              // rows per virtual lane
#define NB 64            // batch elements / blocks
#define NVL 128          // virtual lanes per element
#define BIGV 1.0e10f
#define K2   144.269504089f     // (1/gamma) * log2(e)
#define GLN2 0.00693147181f     // gamma * ln(2)

__device__ __forceinline__ float f4get(const float4& v, int k) {
    switch (k) { case 0: return v.x; case 1: return v.y; case 2: return v.z; default: return v.w; }
}
__device__ __forceinline__ int iclamp(int x, int lo, int hi) {
    return x < lo ? lo : (x > hi ? hi : x);
}
__device__ __forceinline__ float fast_rcp(float x) {
#if __has_builtin(__builtin_amdgcn_rcpf)
    return __builtin_amdgcn_rcpf(x);
#else
    return 1.0f / x;
#endif
}

__global__ __launch_bounds__(128) void dtw_fused(
    const float* __restrict__ D,
    float* __restrict__ out,          // [256][256]
    float* __restrict__ ws)
{
    const int b = blockIdx.x;                        // batch element
    const int L = threadIdx.x;                       // virtual lane 0..127
    const float* __restrict__ th = D + (size_t)b * (MM * NN);
    float* __restrict__ Wl = ws + (size_t)b * (MM * NN);               // becomes E plane
    float* __restrict__ Wu = ws + (size_t)NB * (MM * NN) + (size_t)b * (MM * NN);
    unsigned* ctr = (unsigned*)(ws + (size_t)2 * NB * (MM * NN));

    // neighbor-exchange slots (double-buffered by macro-step parity).
    // fwd: lane L writes xb[p][L+1], reads xb[p][L]; xb[p][0] = BIGV sentinel.
    // bwd: lane L writes {wb,ub,eb}[p][L], reads [L+1]; [p][NVL] = 0 sentinel.
    __shared__ float4 xb[2][NVL + 1];
    __shared__ float4 wb[2][NVL + 1], ub[2][NVL + 1], eb[2][NVL + 1];

    // ---------------- forward ----------------
    {
        float vprev[R];
        #pragma unroll
        for (int r = 0; r < R; ++r) vprev[r] = BIGV;
        float4 rec = make_float4(BIGV, BIGV, BIGV, BIGV);
        float prevW = BIGV;
        float4 botV4 = make_float4(BIGV, BIGV, BIGV, BIGV);
        float4 thB[3][R];
        #pragma unroll
        for (int p = 0; p < 3; ++p)
            #pragma unroll
            for (int r = 0; r < R; ++r) thB[p][r] = make_float4(0.f, 0.f, 0.f, 0.f);

        if (threadIdx.x == 0) {
            xb[0][0] = make_float4(BIGV, BIGV, BIGV, BIGV);
            xb[1][0] = make_float4(BIGV, BIGV, BIGV, BIGV);
        }
        __syncthreads();

        auto fwd_body = [&](const int LD, const int CU, const int m) {
            const int g = m - L;
            const int gl = iclamp(g + 2, 0, 63);
            #pragma unroll
            for (int r = 0; r < R; ++r)
                thB[LD][r] = *(const float4*)(th + (2 * L + r) * NN + 4 * gl);
            if (g >= 0 && g <= 63) {
                const float4 topV = rec;             // rows above, cols 4g+1..4g+4
                const float vd0 = (g == 0) ? ((L == 0) ? 0.0f : BIGV) : prevW;
                float wlb[R][4], wub[R][4];
                #pragma unroll
                for (int cc = 0; cc < 4; ++cc) {
                    float vu = f4get(topV, cc);
                    float vd = (cc == 0) ? vd0 : f4get(topV, cc - 1);
                    #pragma unroll
                    for (int r = 0; r < R; ++r) {
                        const float vl = vprev[r];
                        const float mn = fminf(vl, fminf(vd, vu));
                        const float el = exp2f((mn - vl) * K2);
                        const float ed = exp2f((mn - vd) * K2);
                        const float eu = exp2f((mn - vu) * K2);
                        const float ss = el + ed + eu;
                        const float ri = fast_rcp(ss);
                        const float a  = mn - GLN2 * log2f(ss);
                        const float v  = a + f4get(thB[CU][r], cc);
                        wlb[r][cc] = el * ri;
                        wub[r][cc] = eu * ri;
                        vd = vl;
                        vu = v;
                        vprev[r] = v;
                    }
                    f4get(botV4, 0);  // no-op keep
                    if (cc == 0) botV4.x = vprev[R - 1];
                    else if (cc == 1) botV4.y = vprev[R - 1];
                    else if (cc == 2) botV4.z = vprev[R - 1];
                    else botV4.w = vprev[R - 1];
                }
                #pragma unroll
                for (int r = 0; r < R; ++r) {
                    *(float4*)(Wl + (2 * L + r) * NN + 4 * g) =
                        make_float4(wlb[r][0], wlb[r][1], wlb[r][2], wlb[r][3]);
                    *(float4*)(Wu + (2 * L + r) * NN + 4 * g) =
                        make_float4(wub[r][0], wub[r][1], wub[r][2], wub[r][3]);
                }
            }
            // ---- branch-free exchange ----
            xb[m & 1][L + 1] = botV4;
            __syncthreads();
            prevW = rec.w;
            rec = xb[m & 1][L];
        };
        for (int k = 0; k < 195; k += 3) {      // m = -2 .. 192
            fwd_body(0, 1, k - 2);
            fwd_body(1, 2, k - 1);
            fwd_body(2, 0, k);
        }
    }

    __threadfence();   // order forward weight-stores before backward loads

    // ---------------- backward (pure FMA, E -> Wl plane in place) ----------------
    {
        float eprev[R], prevWl[R], prevWu[R];
        #pragma unroll
        for (int r = 0; r < R; ++r) { eprev[r] = 0.0f; prevWl[r] = 0.0f; prevWu[r] = 0.0f; }
        float4 WlB[3][R], WuB[3][R];
        #pragma unroll
        for (int p = 0; p < 3; ++p)
            #pragma unroll
            for (int r = 0; r < R; ++r) {
                WlB[p][r] = make_float4(0.f, 0.f, 0.f, 0.f);
                WuB[p][r] = make_float4(0.f, 0.f, 0.f, 0.f);
            }
        float4 recWd = make_float4(0.f, 0.f, 0.f, 0.f);
        float4 recWu = recWd, recE = recWd;
        float pWd = 0.0f, pE = 0.0f;
        float4 topWd4 = recWd, topWu4 = recWd, topE4 = recWd;

        if (threadIdx.x == 0) {
            const float4 z = make_float4(0.f, 0.f, 0.f, 0.f);
            wb[0][NVL] = z; wb[1][NVL] = z;
            ub[0][NVL] = z; ub[1][NVL] = z;
            eb[0][NVL] = z; eb[1][NVL] = z;
        }
        __syncthreads();

        auto bwd_body = [&](const int LD, const int CU, const int m) {
            const int g = 190 - m - L;
            const int gl = iclamp(g - 2, 0, 63);
            #pragma unroll
            for (int r = 0; r < R; ++r) {
                WlB[LD][r] = *(const float4*)(Wl + (2 * L + r) * NN + 4 * gl);
                WuB[LD][r] = *(const float4*)(Wu + (2 * L + r) * NN + 4 * gl);
            }
            if (g >= 0 && g <= 63) {
                const float pWd_ = (g == 63) ? 0.0f : pWd;
                const float pE_  = (g == 63) ? 0.0f : pE;
                float ebuf[R][4];
                #pragma unroll
                for (int cc = 3; cc >= 0; --cc) {
                    float bWd = (cc == 3) ? pWd_ : f4get(recWd, cc + 1);  // wd(i+1, c+1)
                    float bEo = (cc == 3) ? pE_  : f4get(recE,  cc + 1);  // E (i+1, c+1)
                    float bWu = f4get(recWu, cc);                         // wu(i+1, c)
                    float bEn = f4get(recE,  cc);                         // E (i+1, c)
                    #pragma unroll
                    for (int r = R - 1; r >= 0; --r) {
                        const float wlr = (cc == 3) ? prevWl[r] : f4get(WlB[CU][r], cc + 1);
                        float e = wlr * eprev[r] + bWd * bEo + bWu * bEn;
                        if (L == NVL - 1 && r == R - 1 && g == 63 && cc == 3)
                            e = 1.0f;                                   // seed E(M,N)
                        ebuf[r][cc] = e;
                        const float wu_b = (cc == 3) ? prevWu[r] : f4get(WuB[CU][r], cc + 1);
                        bWd = 1.0f - wlr - wu_b;
                        bWu = f4get(WuB[CU][r], cc);
                        bEo = eprev[r];
                        bEn = e;
                        eprev[r] = e;
                    }
                }
                topWd4 = make_float4(
                    1.0f - WlB[CU][0].x - WuB[CU][0].x,
                    1.0f - WlB[CU][0].y - WuB[CU][0].y,
                    1.0f - WlB[CU][0].z - WuB[CU][0].z,
                    1.0f - WlB[CU][0].w - WuB[CU][0].w);
                topWu4 = WuB[CU][0];
                topE4  = make_float4(ebuf[0][0], ebuf[0][1], ebuf[0][2], ebuf[0][3]);
                #pragma unroll
                for (int r = 0; r < R; ++r)                     // E in place of Wl
                    *(float4*)(Wl + (2 * L + r) * NN + 4 * g) =
                        make_float4(ebuf[r][0], ebuf[r][1], ebuf[r][2], ebuf[r][3]);
            }
            // ---- branch-free exchange ----
            wb[m & 1][L] = topWd4;
            ub[m & 1][L] = topWu4;
            eb[m & 1][L] = topE4;
            __syncthreads();
            pWd = recWd.x; pE = recE.x;
            #pragma unroll
            for (int r = 0; r < R; ++r) {        // own-row W at next group's col0
                prevWl[r] = WlB[CU][r].x;
                prevWu[r] = WuB[CU][r].x;
            }
            recWd = wb[m & 1][L + 1];
            recWu = ub[m & 1][L + 1];
            recE  = eb[m & 1][L + 1];
        };
        for (int k = 0; k < 195; k += 3) {      // m = -2 .. 192
            bwd_body(0, 1, k - 2);
            bwd_body(1, 2, k - 1);
            bwd_body(2, 0, k);
        }
    }

    // ---------------- device-scope barrier (64 blocks) + slice reduction ----------------
    __threadfence();                               // release E stores (L2 writeback)
    if (threadIdx.x == 0)
        __hip_atomic_fetch_add(ctr, 1u, __ATOMIC_ACQ_REL, __HIP_MEMORY_SCOPE_AGENT);
    unsigned cnt;
    do {
        cnt = __hip_atomic_load(ctr, __ATOMIC_ACQUIRE, __HIP_MEMORY_SCOPE_AGENT);
        if (cnt < NB) __builtin_amdgcn_s_sleep(2);
    } while (cnt < NB);
    __builtin_amdgcn_fence(__ATOMIC_ACQUIRE, "agent");   // invalidate caches

    {
        const float* Eall = ws;                    // Wl planes now hold E
        float4 acc[2];
        #pragma unroll
        for (int k2 = 0; k2 < 2; ++k2) acc[k2] = make_float4(0.f, 0.f, 0.f, 0.f);
        for (int p = 0; p < NB; ++p) {
            const float* Ep = Eall + (size_t)p * (MM * NN);
            #pragma unroll
            for (int k2 = 0; k2 < 2; ++k2) {
                const float4 v = *(const float4*)(Ep + 1024 * b + 512 * k2 + 4 * threadIdx.x);
                acc[k2].x += v.x; acc[k2].y += v.y; acc[k2].z += v.z; acc[k2].w += v.w;
            }
        }
        const float inv = 1.0f / (float)NB;
        #pragma unroll
        for (int k2 = 0; k2 < 2; ++k2)
            *(float4*)(out + 1024 * b + 512 * k2 + 4 * threadIdx.x) =
                make_float4(acc[k2].x * inv, acc[k2].y * inv, acc[k2].z * inv, acc[k2].w * inv);
    }
}

extern "C" void kernel_launch(void* const* d_in, const int* in_sizes, int n_in,
                              void* d_out, int out_size, void* d_ws, size_t ws_size,
                              hipStream_t stream) {
    const float* D = (const float*)d_in[0];
    float* out = (float*)d_out;
    float* ws = (float*)d_ws;

    // zero the barrier counter (ws is re-poisoned 0xAA before every launch)
    hipMemsetAsync(ws + (size_t)2 * NB * (MM * NN), 0, sizeof(unsigned), stream);
    dtw_fused<<<dim3(NB), dim3(128), 0, stream>>>(D, out, ws);
}

// Round 12
// 325.852 us; speedup vs baseline: 3.6258x; 1.0118x over previous
//
#include <hip/hip_runtime.h>

// Soft-DTW gradient, batch=64, 256x256, gamma=0.01 — single fused kernel.
// R12 = R11 + LDS-only barrier: the per-body __syncthreads() compiled to
// "s_waitcnt vmcnt(0) expcnt(0) lgkmcnt(0); s_barrier", force-draining the
// distance-2 global prefetch every macro-step. Replaced with inline-asm
// "s_waitcnt lgkmcnt(0); s_barrier" (LDS visibility only) so global loads
// stay in flight across the exchange barrier.
// Layout: 64 blocks x 128 threads. Each block = one batch element, two
// waves on different SIMDs of one CU. Virtual lane L owns rows 2L+1, 2L+2.
// 4-column skew: lane L does column-group g at macro-step m = g + L (fwd)
// / m = 190 - g - L (bwd). Branch-free double-buffered LDS neighbor
// exchange with sentinel slots. Forward stores softmin weights (wl, wu);
// backward pure FMA, E in-place over Wl. Device-scope flag barrier, then
// per-block slice reduction. No atomics on out. 3-phase rotating prefetch.
// ws: Wl/E planes [64][65536] f32, Wu planes [64][65536] f32, counter u32.

#define MM 256
#define NN 256
#define R 2              // rows per virtual lane
#define NB 64            // batch elements / blocks
#define NVL 128          // virtual lanes per element
#define BIGV 1.0e10f
#define K2   144.269504089f     // (1/gamma) * log2(e)
#define GLN2 0.00693147181f     // gamma * ln(2)

__device__ __forceinline__ float f4get(const float4& v, int k) {
    switch (k) { case 0: return v.x; case 1: return v.y; case 2: return v.z; default: return v.w; }
}
__device__ __forceinline__ int iclamp(int x, int lo, int hi) {
    return x < lo ? lo : (x > hi ? hi : x);
}
__device__ __forceinline__ float fast_rcp(float x) {
#if __has_builtin(__builtin_amdgcn_rcpf)
    return __builtin_amdgcn_rcpf(x);
#else
    return 1.0f / x;
#endif
}
// LDS-visibility-only workgroup barrier: does NOT drain vmcnt, so global
// prefetch loads / weight stores stay in flight across it.
__device__ __forceinline__ void lds_barrier() {
    asm volatile("s_waitcnt lgkmcnt(0)\n\ts_barrier" ::: "memory");
}

__global__ __launch_bounds__(128) void dtw_fused(
    const float* __restrict__ D,
    float* __restrict__ out,          // [256][256]
    float* __restrict__ ws)
{
    const int b = blockIdx.x;                        // batch element
    const int L = threadIdx.x;                       // virtual lane 0..127
    const float* __restrict__ th = D + (size_t)b * (MM * NN);
    float* __restrict__ Wl = ws + (size_t)b * (MM * NN);               // becomes E plane
    float* __restrict__ Wu = ws + (size_t)NB * (MM * NN) + (size_t)b * (MM * NN);
    unsigned* ctr = (unsigned*)(ws + (size_t)2 * NB * (MM * NN));

    // neighbor-exchange slots (double-buffered by macro-step parity).
    // fwd: lane L writes xb[p][L+1], reads xb[p][L]; xb[p][0] = BIGV sentinel.
    // bwd: lane L writes {wb,ub,eb}[p][L], reads [L+1]; [p][NVL] = 0 sentinel.
    __shared__ float4 xb[2][NVL + 1];
    __shared__ float4 wb[2][NVL + 1], ub[2][NVL + 1], eb[2][NVL + 1];

    // ---------------- forward ----------------
    {
        float vprev[R];
        #pragma unroll
        for (int r = 0; r < R; ++r) vprev[r] = BIGV;
        float4 rec = make_float4(BIGV, BIGV, BIGV, BIGV);
        float prevW = BIGV;
        float4 botV4 = make_float4(BIGV, BIGV, BIGV, BIGV);
        float4 thB[3][R];
        #pragma unroll
        for (int p = 0; p < 3; ++p)
            #pragma unroll
            for (int r = 0; r < R; ++r) thB[p][r] = make_float4(0.f, 0.f, 0.f, 0.f);

        if (threadIdx.x == 0) {
            xb[0][0] = make_float4(BIGV, BIGV, BIGV, BIGV);
            xb[1][0] = make_float4(BIGV, BIGV, BIGV, BIGV);
        }
        __syncthreads();

        auto fwd_body = [&](const int LD, const int CU, const int m) {
            const int g = m - L;
            const int gl = iclamp(g + 2, 0, 63);
            #pragma unroll
            for (int r = 0; r < R; ++r)
                thB[LD][r] = *(const float4*)(th + (2 * L + r) * NN + 4 * gl);
            if (g >= 0 && g <= 63) {
                const float4 topV = rec;             // rows above, cols 4g+1..4g+4
                const float vd0 = (g == 0) ? ((L == 0) ? 0.0f : BIGV) : prevW;
                float wlb[R][4], wub[R][4];
                #pragma unroll
                for (int cc = 0; cc < 4; ++cc) {
                    float vu = f4get(topV, cc);
                    float vd = (cc == 0) ? vd0 : f4get(topV, cc - 1);
                    #pragma unroll
                    for (int r = 0; r < R; ++r) {
                        const float vl = vprev[r];
                        const float mn = fminf(vl, fminf(vd, vu));
                        const float el = exp2f((mn - vl) * K2);
                        const float ed = exp2f((mn - vd) * K2);
                        const float eu = exp2f((mn - vu) * K2);
                        const float ss = el + ed + eu;
                        const float ri = fast_rcp(ss);
                        const float a  = mn - GLN2 * log2f(ss);
                        const float v  = a + f4get(thB[CU][r], cc);
                        wlb[r][cc] = el * ri;
                        wub[r][cc] = eu * ri;
                        vd = vl;
                        vu = v;
                        vprev[r] = v;
                    }
                    if (cc == 0) botV4.x = vprev[R - 1];
                    else if (cc == 1) botV4.y = vprev[R - 1];
                    else if (cc == 2) botV4.z = vprev[R - 1];
                    else botV4.w = vprev[R - 1];
                }
                #pragma unroll
                for (int r = 0; r < R; ++r) {
                    *(float4*)(Wl + (2 * L + r) * NN + 4 * g) =
                        make_float4(wlb[r][0], wlb[r][1], wlb[r][2], wlb[r][3]);
                    *(float4*)(Wu + (2 * L + r) * NN + 4 * g) =
                        make_float4(wub[r][0], wub[r][1], wub[r][2], wub[r][3]);
                }
            }
            // ---- branch-free exchange (LDS-only barrier) ----
            xb[m & 1][L + 1] = botV4;
            lds_barrier();
            prevW = rec.w;
            rec = xb[m & 1][L];
        };
        for (int k = 0; k < 195; k += 3) {      // m = -2 .. 192
            fwd_body(0, 1, k - 2);
            fwd_body(1, 2, k - 1);
            fwd_body(2, 0, k);
        }
    }

    __syncthreads();
    __threadfence();   // order forward weight-stores before backward loads

    // ---------------- backward (pure FMA, E -> Wl plane in place) ----------------
    {
        float eprev[R], prevWl[R], prevWu[R];
        #pragma unroll
        for (int r = 0; r < R; ++r) { eprev[r] = 0.0f; prevWl[r] = 0.0f; prevWu[r] = 0.0f; }
        float4 WlB[3][R], WuB[3][R];
        #pragma unroll
        for (int p = 0; p < 3; ++p)
            #pragma unroll
            for (int r = 0; r < R; ++r) {
                WlB[p][r] = make_float4(0.f, 0.f, 0.f, 0.f);
                WuB[p][r] = make_float4(0.f, 0.f, 0.f, 0.f);
            }
        float4 recWd = make_float4(0.f, 0.f, 0.f, 0.f);
        float4 recWu = recWd, recE = recWd;
        float pWd = 0.0f, pE = 0.0f;
        float4 topWd4 = recWd, topWu4 = recWd, topE4 = recWd;

        if (threadIdx.x == 0) {
            const float4 z = make_float4(0.f, 0.f, 0.f, 0.f);
            wb[0][NVL] = z; wb[1][NVL] = z;
            ub[0][NVL] = z; ub[1][NVL] = z;
            eb[0][NVL] = z; eb[1][NVL] = z;
        }
        __syncthreads();

        auto bwd_body = [&](const int LD, const int CU, const int m) {
            const int g = 190 - m - L;
            const int gl = iclamp(g - 2, 0, 63);
            #pragma unroll
            for (int r = 0; r < R; ++r) {
                WlB[LD][r] = *(const float4*)(Wl + (2 * L + r) * NN + 4 * gl);
                WuB[LD][r] = *(const float4*)(Wu + (2 * L + r) * NN + 4 * gl);
            }
            if (g >= 0 && g <= 63) {
                const float pWd_ = (g == 63) ? 0.0f : pWd;
                const float pE_  = (g == 63) ? 0.0f : pE;
                float ebuf[R][4];
                #pragma unroll
                for (int cc = 3; cc >= 0; --cc) {
                    float bWd = (cc == 3) ? pWd_ : f4get(recWd, cc + 1);  // wd(i+1, c+1)
                    float bEo = (cc == 3) ? pE_  : f4get(recE,  cc + 1);  // E (i+1, c+1)
                    float bWu = f4get(recWu, cc);                         // wu(i+1, c)
                    float bEn = f4get(recE,  cc);                         // E (i+1, c)
                    #pragma unroll
                    for (int r = R - 1; r >= 0; --r) {
                        const float wlr = (cc == 3) ? prevWl[r] : f4get(WlB[CU][r], cc + 1);
                        float e = wlr * eprev[r] + bWd * bEo + bWu * bEn;
                        if (L == NVL - 1 && r == R - 1 && g == 63 && cc == 3)
                            e = 1.0f;                                   // seed E(M,N)
                        ebuf[r][cc] = e;
                        const float wu_b = (cc == 3) ? prevWu[r] : f4get(WuB[CU][r], cc + 1);
                        bWd = 1.0f - wlr - wu_b;
                        bWu = f4get(WuB[CU][r], cc);
                        bEo = eprev[r];
                        bEn = e;
                        eprev[r] = e;
                    }
                }
                topWd4 = make_float4(
                    1.0f - WlB[CU][0].x - WuB[CU][0].x,
                    1.0f - WlB[CU][0].y - WuB[CU][0].y,
                    1.0f - WlB[CU][0].z - WuB[CU][0].z,
                    1.0f - WlB[CU][0].w - WuB[CU][0].w);
                topWu4 = WuB[CU][0];
                topE4  = make_float4(ebuf[0][0], ebuf[0][1], ebuf[0][2], ebuf[0][3]);
                #pragma unroll
                for (int r = 0; r < R; ++r)                     // E in place of Wl
                    *(float4*)(Wl + (2 * L + r) * NN + 4 * g) =
                        make_float4(ebuf[r][0], ebuf[r][1], ebuf[r][2], ebuf[r][3]);
            }
            // ---- branch-free exchange (LDS-only barrier) ----
            wb[m & 1][L] = topWd4;
            ub[m & 1][L] = topWu4;
            eb[m & 1][L] = topE4;
            lds_barrier();
            pWd = recWd.x; pE = recE.x;
            #pragma unroll
            for (int r = 0; r < R; ++r) {        // own-row W at next group's col0
                prevWl[r] = WlB[CU][r].x;
                prevWu[r] = WuB[CU][r].x;
            }
            recWd = wb[m & 1][L + 1];
            recWu = ub[m & 1][L + 1];
            recE  = eb[m & 1][L + 1];
        };
        for (int k = 0; k < 195; k += 3) {      // m = -2 .. 192
            bwd_body(0, 1, k - 2);
            bwd_body(1, 2, k - 1);
            bwd_body(2, 0, k);
        }
    }

    // ---------------- device-scope barrier (64 blocks) + slice reduction ----------------
    __threadfence();                               // release E stores (L2 writeback)
    if (threadIdx.x == 0)
        __hip_atomic_fetch_add(ctr, 1u, __ATOMIC_ACQ_REL, __HIP_MEMORY_SCOPE_AGENT);
    unsigned cnt;
    do {
        cnt = __hip_atomic_load(ctr, __ATOMIC_ACQUIRE, __HIP_MEMORY_SCOPE_AGENT);
        if (cnt < NB) __builtin_amdgcn_s_sleep(2);
    } while (cnt < NB);
    __builtin_amdgcn_fence(__ATOMIC_ACQUIRE, "agent");   // invalidate caches

    {
        const float* Eall = ws;                    // Wl planes now hold E
        float4 acc[2];
        #pragma unroll
        for (int k2 = 0; k2 < 2; ++k2) acc[k2] = make_float4(0.f, 0.f, 0.f, 0.f);
        for (int p = 0; p < NB; ++p) {
            const float* Ep = Eall + (size_t)p * (MM * NN);
            #pragma unroll
            for (int k2 = 0; k2 < 2; ++k2) {
                const float4 v = *(const float4*)(Ep + 1024 * b + 512 * k2 + 4 * threadIdx.x);
                acc[k2].x += v.x; acc[k2].y += v.y; acc[k2].z += v.z; acc[k2].w += v.w;
            }
        }
        const float inv = 1.0f / (float)NB;
        #pragma unroll
        for (int k2 = 0; k2 < 2; ++k2)
            *(float4*)(out + 1024 * b + 512 * k2 + 4 * threadIdx.x) =
                make_float4(acc[k2].x * inv, acc[k2].y * inv, acc[k2].z * inv, acc[k2].w * inv);
    }
}

extern "C" void kernel_launch(void* const* d_in, const int* in_sizes, int n_in,
                              void* d_out, int out_size, void* d_ws, size_t ws_size,
                              hipStream_t stream) {
    const float* D = (const float*)d_in[0];
    float* out = (float*)d_out;
    float* ws = (float*)d_ws;

    // zero the barrier counter (ws is re-poisoned 0xAA before every launch)
    hipMemsetAsync(ws + (size_t)2 * NB * (MM * NN), 0, sizeof(unsigned), stream);
    dtw_fused<<<dim3(NB), dim3(128), 0, stream>>>(D, out, ws);
}